// Round 7
// baseline (426.385 us; speedup 1.0000x reference)
//
#include <hip/hip_runtime.h>
#include <hip/hip_bf16.h>

// CapsuleLayer dynamic routing, MI355X.
// B=32,N=2048,D=32 inputs; C=64,V=32 output caps; 3 routing rounds.
// u_hat computed once via bf16 MFMA -> ws; 3 fused routing passes.
// Round 7: uh layout [n][ptile=128][b=32][psub=16] == exact MFMA production
// order. Wave stages 8 ptiles (8KB) in a wave-private padded LDS slice
// (b-stride 20 shorts: minimum-pass bank access on both ds_write_b64 and
// ds_read_b64), flushes as 8 x 1KB perfectly dense store instructions ->
// fillBuffer-shaped linear write stream (the one pattern proven at 6.6 TB/s).
// No barriers/waitcnt drains: per-wave slice, same-wave DS ops are in-order;
// sched_barrier(0) pair per group only blocks compiler cross-lane reorder.
// Routing: waves 0-1 do b, waves 2-3 do b+1 so the split 16B reads of the new
// layout consume full cache lines within one block.

#define B_ 32
#define N_ 2048
#define D_ 32
#define C_ 64
#define V_ 32

typedef __attribute__((ext_vector_type(4))) float f32x4;
typedef __attribute__((ext_vector_type(4))) int i32x4;
typedef __attribute__((ext_vector_type(2))) int i32x2;
typedef __bf16 bf16x8 __attribute__((ext_vector_type(8)));

__device__ __forceinline__ unsigned f2bf1(float f) {
  unsigned u = __builtin_bit_cast(unsigned, f);
  return (u + 0x7FFFu + ((u >> 16) & 1u)) >> 16;  // RNE
}
__device__ __forceinline__ float bf2f(unsigned h) {
  unsigned u = h << 16;
  return __builtin_bit_cast(float, u);
}

__device__ __forceinline__ bf16x8 cvt_frag(f32x4 lo, f32x4 hi) {
  i32x4 r;
  r[0] = f2bf1(lo[0]) | (f2bf1(lo[1]) << 16);
  r[1] = f2bf1(lo[2]) | (f2bf1(lo[3]) << 16);
  r[2] = f2bf1(hi[0]) | (f2bf1(hi[1]) << 16);
  r[3] = f2bf1(hi[2]) | (f2bf1(hi[3]) << 16);
  return __builtin_bit_cast(bf16x8, r);
}

// u_hat bf16, layout uh[n][ptile][b][psub]: elem = ((n*128+pt)*32+b)*16+psub,
// p = pt*16 + psub = c*32 + v. Block = one n, 4 waves; wave owns 32 ptiles.
// A-frag = W (lane l16 = p-row), B-frag = x (lane l16 = b). D: lane holds
// b = bt*16+l16, psub = kg*4+j (4 consecutive) -> one 8B LDS write.
__global__ __launch_bounds__(256) void uhat_kernel(const float* __restrict__ x,
                                                   const float* __restrict__ W,
                                                   unsigned short* __restrict__ uh) {
  const int n = blockIdx.x;
  const int wave = threadIdx.x >> 6;
  const int l = threadIdx.x & 63;
  const int l16 = l & 15, kg = l >> 4;  // frag: row/col = l16, k = kg*8 + i

  // wave-private staging: [pq=8][b=32][psub padded 16->20]; 10 KB/wave.
  __shared__ unsigned short lds[4][8 * 640];
  unsigned short* wlds = lds[wave];

  // B-operand = x: lane l16 = col b (+16 per bt), elems k = kg*8..kg*8+7
  bf16x8 xb[2];
#pragma unroll
  for (int bt = 0; bt < 2; ++bt) {
    const float* xp = x + (((size_t)(bt * 16 + l16)) * N_ + n) * D_ + kg * 8;
    xb[bt] = cvt_frag(*(const f32x4*)xp, *(const f32x4*)(xp + 4));
  }
  const f32x4 zero = {0.f, 0.f, 0.f, 0.f};
  const float* wbase = W + ((size_t)n * 2048 + wave * 512 + l16) * D_ + kg * 8;
  // flush: instr k stores elems tile*512 + l*8, tile = wave*32 + g*8 + k
  unsigned short* ubase = uh + (((size_t)n * 128 + wave * 32) * 512) + l * 8;

  // 2-deep W prefetch ring (compile-time indices via full unroll)
  f32x4 wl[2][2];
  {
    const float* w0 = wbase;
    const float* w1 = wbase + (size_t)16 * D_;
    wl[0][0] = *(const f32x4*)w0; wl[0][1] = *(const f32x4*)(w0 + 4);
    wl[1][0] = *(const f32x4*)w1; wl[1][1] = *(const f32x4*)(w1 + 4);
  }

#pragma unroll
  for (int g = 0; g < 4; ++g) {
#pragma unroll
    for (int pq = 0; pq < 8; ++pq) {
      const int pt = g * 8 + pq;
      f32x4 c0 = wl[pt & 1][0], c1 = wl[pt & 1][1];
      if (pt < 30) {
        const float* wp = wbase + (size_t)((pt + 2) * 16) * D_;
        wl[pt & 1][0] = *(const f32x4*)wp;
        wl[pt & 1][1] = *(const f32x4*)(wp + 4);
      }
      bf16x8 wfrag = cvt_frag(c0, c1);
#pragma unroll
      for (int bt = 0; bt < 2; ++bt) {
        f32x4 acc = __builtin_amdgcn_mfma_f32_16x16x32_bf16(wfrag, xb[bt], zero, 0, 0, 0);
        i32x2 dv;
        dv[0] = (int)(f2bf1(acc[0]) | (f2bf1(acc[1]) << 16));
        dv[1] = (int)(f2bf1(acc[2]) | (f2bf1(acc[3]) << 16));
        // elem = pq*640 + b*20 + psub, b = bt*16+l16, psub = kg*4
        *(i32x2*)(wlds + pq * 640 + (bt * 16 + l16) * 20 + kg * 4) = dv;
      }
    }
    __builtin_amdgcn_sched_barrier(0);  // writes (cross-lane producers) stay above reads
#pragma unroll
    for (int k = 0; k < 8; ++k) {
      // lane l gathers b = l>>1, psub = (l&1)*8 .. +8  (8B-aligned b64 reads)
      const unsigned short* src = wlds + k * 640 + (l >> 1) * 20 + (l & 1) * 8;
      i32x2 lo = *(const i32x2*)src;
      i32x2 hi = *(const i32x2*)(src + 4);
      i32x4 vv;
      vv[0] = lo[0]; vv[1] = lo[1]; vv[2] = hi[0]; vv[3] = hi[1];
      *(i32x4*)(ubase + ((size_t)(g * 8 + k)) * 512) = vv;  // 1KB dense/instr
    }
    __builtin_amdgcn_sched_barrier(0);  // reads complete ordering before next group's writes
  }
}

// Routing pass: s[b,c,v] = sum_n softmax_c(u_hat.vsum)[c] * u_hat[b,n,c,v].
// lane l == c. Block: waves 0,1 -> b = pair*2 (+n halves), waves 2,3 -> b+1.
// Grid = 16 pairs x 32 chunks of 64 n. Partials (no atomics) to ws.
template <int ROUND>
__global__ __launch_bounds__(256) void routing_kernel(const unsigned short* __restrict__ uh,
                                                      const float* __restrict__ vsum,
                                                      float* __restrict__ part) {
  const int pair = blockIdx.x >> 5;
  const int chunk = blockIdx.x & 31;
  const int w = threadIdx.x >> 6;
  const int l = threadIdx.x & 63;  // = c
  const int b = pair * 2 + (w >> 1);
  const int n0 = chunk * 64 + (w & 1) * 32;

  float vs[32];
  if (ROUND >= 2) {
    const f32x4* vp = (const f32x4*)(vsum + ((size_t)b * 64 + l) * 32);
#pragma unroll
    for (int i = 0; i < 8; ++i) {
      f32x4 t = vp[i];
      vs[4 * i] = t[0]; vs[4 * i + 1] = t[1]; vs[4 * i + 2] = t[2]; vs[4 * i + 3] = t[3];
    }
  }
  float sacc[32];
#pragma unroll
  for (int v = 0; v < 32; ++v) sacc[v] = 0.f;

  for (int ni = 0; ni < 32; ++ni) {
    const int n = n0 + ni;
    // p = l*32 + v: tiles 2l, 2l+1; b-chunk of 16 psub each
    const unsigned short* up = uh + (((size_t)n * 128 + 2 * l) * 32 + b) * 16;
    i32x4 qs0 = *(const i32x4*)up;           // v 0..7
    i32x4 qs1 = *(const i32x4*)(up + 8);     // v 8..15
    i32x4 qs2 = *(const i32x4*)(up + 512);   // v 16..23 (next ptile)
    i32x4 qs3 = *(const i32x4*)(up + 520);   // v 24..31
    float u[32];
#pragma unroll
    for (int i = 0; i < 4; ++i) {
      unsigned v0 = (unsigned)qs0[i], v1 = (unsigned)qs1[i], v2 = (unsigned)qs2[i], v3 = (unsigned)qs3[i];
      u[0 + 2 * i] = bf2f(v0 & 0xffffu);  u[0 + 2 * i + 1] = bf2f(v0 >> 16);
      u[8 + 2 * i] = bf2f(v1 & 0xffffu);  u[8 + 2 * i + 1] = bf2f(v1 >> 16);
      u[16 + 2 * i] = bf2f(v2 & 0xffffu); u[16 + 2 * i + 1] = bf2f(v2 >> 16);
      u[24 + 2 * i] = bf2f(v3 & 0xffffu); u[24 + 2 * i + 1] = bf2f(v3 >> 16);
    }
    float r;
    if (ROUND >= 2) {
      float br = 0.f;
#pragma unroll
      for (int v = 0; v < 32; ++v) br = fmaf(u[v], vs[v], br);
      float m = br;
#pragma unroll
      for (int off = 32; off; off >>= 1) m = fmaxf(m, __shfl_xor(m, off, 64));
      float e = __expf(br - m);
      float den = e;
#pragma unroll
      for (int off = 32; off; off >>= 1) den += __shfl_xor(den, off, 64);
      r = e / den;
    } else {
      r = 1.0f / 64.0f;  // softmax of zeros
    }
#pragma unroll
    for (int v = 0; v < 32; ++v) sacc[v] = fmaf(r, u[v], sacc[v]);
  }

  __shared__ float red[4][64][33];  // +1 pad: conflict-free
#pragma unroll
  for (int v = 0; v < 32; ++v) red[w][l][v] = sacc[v];
  __syncthreads();
  const int t = threadIdx.x;
  f32x4 o0, o1, p0, p1;
#pragma unroll
  for (int i = 0; i < 4; ++i) {
    const int e0 = t * 8 + i, e1 = t * 8 + 4 + i;
    o0[i] = red[0][e0 >> 5][e0 & 31] + red[1][e0 >> 5][e0 & 31];  // b = pair*2
    o1[i] = red[0][e1 >> 5][e1 & 31] + red[1][e1 >> 5][e1 & 31];
    p0[i] = red[2][e0 >> 5][e0 & 31] + red[3][e0 >> 5][e0 & 31];  // b = pair*2+1
    p1[i] = red[2][e1 >> 5][e1 & 31] + red[3][e1 >> 5][e1 & 31];
  }
  float* pp0 = part + ((size_t)blockIdx.x * 2) * 2048 + t * 8;
  float* pp1 = part + ((size_t)blockIdx.x * 2 + 1) * 2048 + t * 8;
  *(f32x4*)pp0 = o0;
  *(f32x4*)(pp0 + 4) = o1;
  *(f32x4*)pp1 = p0;
  *(f32x4*)(pp1 + 4) = p1;
}

// Reduce partials -> s, squash -> v. Writes v to out; maintains vsum.
template <int ROUND>
__global__ __launch_bounds__(256) void squash_kernel(const float* __restrict__ part,
                                                     float* __restrict__ vsum,
                                                     float* __restrict__ out) {
  const int t = blockIdx.x * 256 + threadIdx.x;  // b*2048 + c*32 + v
  const int b = t >> 11;
  const int e = t & 2047;
  const int pr = b >> 1, b01 = b & 1;
  float sv = 0.f;
#pragma unroll
  for (int k = 0; k < 32; ++k)
    sv += part[(((size_t)(pr * 32 + k)) * 2 + b01) * 2048 + e];
  float sq = sv * sv;
#pragma unroll
  for (int off = 16; off; off >>= 1) sq += __shfl_xor(sq, off, 64);  // sum over v
  float scale = (sq / (1.f + sq)) * rsqrtf(sq + 1e-9f);
  float val = sv * scale;
  out[t] = val;
  if (ROUND == 1) vsum[t] = val;
  else if (ROUND == 2) vsum[t] += val;
}

extern "C" void kernel_launch(void* const* d_in, const int* in_sizes, int n_in,
                              void* d_out, int out_size, void* d_ws, size_t ws_size,
                              hipStream_t stream) {
  const float* x = (const float*)d_in[0];  // [B,N,D]
  const float* W = (const float*)d_in[1];  // [1,N,C,V,D]
  float* out = (float*)d_out;              // [B,1,C,V,1] = 65536 fp32

  const size_t UH_BYTES = (size_t)B_ * N_ * C_ * V_ * 2;  // 268435456
  const size_t PART_BYTES = (size_t)512 * 2 * 2048 * 4;   // 8388608
  const size_t VSUM_BYTES = (size_t)B_ * C_ * V_ * 4;     // 262144
  if (ws_size < UH_BYTES + PART_BYTES + VSUM_BYTES) return;  // can't run

  unsigned short* uh = (unsigned short*)d_ws;
  float* part = (float*)((char*)d_ws + UH_BYTES);
  float* vsum = (float*)((char*)d_ws + UH_BYTES + PART_BYTES);

  uhat_kernel<<<N_, 256, 0, stream>>>(x, W, uh);
  routing_kernel<1><<<512, 256, 0, stream>>>(uh, vsum, part);
  squash_kernel<1><<<256, 256, 0, stream>>>(part, vsum, out);
  routing_kernel<2><<<512, 256, 0, stream>>>(uh, vsum, part);
  squash_kernel<2><<<256, 256, 0, stream>>>(part, vsum, out);
  routing_kernel<3><<<512, 256, 0, stream>>>(uh, vsum, part);
  squash_kernel<3><<<256, 256, 0, stream>>>(part, vsum, out);
}